// Round 5
// baseline (426.591 us; speedup 1.0000x reference)
//
#include <hip/hip_runtime.h>
#include <hip/hip_bf16.h>

#define B_   2
#define S_   2048
#define D_   1024
#define H_   16
#define HD_  64
#define HID_ 2816

typedef unsigned short u16;
typedef unsigned int   u32;
typedef __attribute__((ext_vector_type(8))) short short8;
typedef __attribute__((ext_vector_type(4))) float f32x4;
typedef __attribute__((ext_vector_type(2))) float f32x2;
typedef __attribute__((ext_vector_type(4))) u32   u32x4;
typedef __attribute__((ext_vector_type(2))) unsigned uvec2;

static __device__ __forceinline__ float bf2f(u16 u){ return __uint_as_float(((u32)u)<<16); }
static __device__ __forceinline__ u16 f2bf(float f){
  u32 u = __float_as_uint(f);
  u32 r = (u + 0x7FFFu + ((u>>16)&1u)) >> 16;   // round-to-nearest-even
  return (u16)r;
}
// round-half-up bf16 (2 ops) and packed pair
static __device__ __forceinline__ u16 f2bfr(float f){
  return (u16)((__float_as_uint(f) + 0x8000u) >> 16);
}
static __device__ __forceinline__ u32 pk2(float a, float b){
  return ((__float_as_uint(a) + 0x8000u) >> 16) | ((__float_as_uint(b) + 0x8000u) & 0xFFFF0000u);
}
// single-instruction packed f32->bf16 pair (lo, hi)
static __device__ __forceinline__ u32 cvtpk(float lo, float hi){
  u32 r; asm("v_cvt_pk_bf16_f32 %0, %1, %2" : "=v"(r) : "v"(lo), "v"(hi)); return r;
}
static __device__ __forceinline__ float vmax3(float a, float b, float c){
  float d; asm("v_max3_f32 %0, %1, %2, %3" : "=v"(d) : "v"(a), "v"(b), "v"(c)); return d;
}
// packed dual-f32 add (VOP3P, CDNA2+): one instr does 2 lanes' worth per lane
static __device__ __forceinline__ f32x2 pkadd(f32x2 a, f32x2 b){
  f32x2 d; asm("v_pk_add_f32 %0, %1, %2" : "=v"(d) : "v"(a), "v"(b)); return d;
}
// cross-lane pair exchange via permlane swaps (VALU, no DS pipe).
// After plswapN(x,a,b): {a[i],b[i]} == {x[i], x[i^N]} for every lane.
static __device__ __forceinline__ void plswap16(float x, float& a, float& b){
#if __has_builtin(__builtin_amdgcn_permlane16_swap)
  uvec2 r = __builtin_amdgcn_permlane16_swap(__float_as_uint(x), __float_as_uint(x), false, false);
  a = __uint_as_float(r[0]); b = __uint_as_float(r[1]);
#else
  a = x; b = __shfl_xor(x, 16, 64);
#endif
}
static __device__ __forceinline__ void plswap32(float x, float& a, float& b){
#if __has_builtin(__builtin_amdgcn_permlane32_swap)
  uvec2 r = __builtin_amdgcn_permlane32_swap(__float_as_uint(x), __float_as_uint(x), false, false);
  a = __uint_as_float(r[0]); b = __uint_as_float(r[1]);
#else
  a = x; b = __shfl_xor(x, 32, 64);
#endif
}

static __device__ __forceinline__ void ld4(const u16* p, float* v){
  ushort4 t = *reinterpret_cast<const ushort4*>(p);
  v[0]=bf2f(t.x); v[1]=bf2f(t.y); v[2]=bf2f(t.z); v[3]=bf2f(t.w);
}
static __device__ __forceinline__ void ld4(const float* p, float* v){
  float4 t = *reinterpret_cast<const float4*>(p);
  v[0]=t.x; v[1]=t.y; v[2]=t.z; v[3]=t.w;
}
static __device__ __forceinline__ void st4(u16* p, const float* v){
  ushort4 t; t.x=f2bf(v[0]); t.y=f2bf(v[1]); t.z=f2bf(v[2]); t.w=f2bf(v[3]);
  *reinterpret_cast<ushort4*>(p)=t;
}

static __device__ __forceinline__ float ld1g(const void* p, size_t i, bool f32){
  return f32 ? ((const float*)p)[i] : bf2f(((const u16*)p)[i]);
}
static __device__ __forceinline__ void ld4g(const void* p, size_t i, float* v, bool f32){
  if(f32){
    float4 t = *reinterpret_cast<const float4*>((const float*)p + i);
    v[0]=t.x; v[1]=t.y; v[2]=t.z; v[3]=t.w;
  }else{
    ushort4 t = *reinterpret_cast<const ushort4*>((const u16*)p + i);
    v[0]=bf2f(t.x); v[1]=bf2f(t.y); v[2]=bf2f(t.z); v[3]=bf2f(t.w);
  }
}
static __device__ __forceinline__ void st4g(void* p, size_t i, const float* v, bool f32){
  if(f32){
    float4 t; t.x=v[0]; t.y=v[1]; t.z=v[2]; t.w=v[3];
    *reinterpret_cast<float4*>((float*)p + i) = t;
  }else{
    st4((u16*)p + i, v);
  }
}

// async global->LDS, 16B per lane
static __device__ __forceinline__ void gl2lds16(const u16* g, const u16* l){
  typedef __attribute__((address_space(3))) u16 lds_u16;
  typedef const __attribute__((address_space(1))) u16 glb_u16;
  __builtin_amdgcn_global_load_lds((glb_u16*)(uintptr_t)g,
                                   (lds_u16*)(u32)(uintptr_t)l, 16, 0, 0);
}

// ---- probe (freqs_cos[0]==1.0f -> fp32 first u16 is 0) + zero m
__global__ __launch_bounds__(256) void k_probe_zero(const u16* fc_raw, int* flag, float* m){
  int i = blockIdx.x*256 + threadIdx.x;
  if(i < 12288) m[i] = 0.f;
  if(i == 0) *flag = (fc_raw[0]==0) ? 1 : 0;
}

static __device__ __forceinline__ float blk_sum(float v, float* red){
  #pragma unroll
  for(int o=32;o;o>>=1) v += __shfl_xor(v,o,64);
  int lane = threadIdx.x & 63, w = threadIdx.x >> 6;
  if(lane==0) red[w]=v;
  __syncthreads();
  float t = red[0]+red[1]+red[2]+red[3];
  __syncthreads();
  return t;
}

// ---- adaLN: m[b][n] = silu(a[b]) . ada_w[:,n] + ada_b[n]
__global__ __launch_bounds__(256) void k_adaln(const void* a, const void* W, const void* bias,
                                               float* m, const int* flag){
  bool f32 = flag[0] != 0;
  __shared__ float sl[2][128];
  int bk = blockIdx.y;
  {
    int bb = threadIdx.x >> 7, kk = threadIdx.x & 127;
    float x = ld1g(a, bb*D_ + bk*128 + kk, f32);
    sl[bb][kk] = x/(1.f+__expf(-x));
  }
  __syncthreads();
  int n = blockIdx.x*256 + threadIdx.x;
  float p0 = 0.f, p1 = 0.f;
  for(int kk=0;kk<128;kk++){
    float w = ld1g(W, (size_t)(bk*128+kk)*6144 + n, f32);
    p0 += sl[0][kk]*w; p1 += sl[1][kk]*w;
  }
  if(bk==0){ float bv = ld1g(bias, n, f32); p0 += bv; p1 += bv; }
  atomicAdd(&m[n], p0);
  atomicAdd(&m[6144+n], p1);
}

__global__ __launch_bounds__(256) void k_rms_mod(const void* x, const void* nw, const float* m,
                                                 u16* h, int shift_off, int scale_off,
                                                 const int* flag){
  bool f32 = flag[0] != 0;
  __shared__ float red[4];
  int row = blockIdx.x; int b = row >> 11;
  int d0 = threadIdx.x*4;
  float v[4]; ld4g(x, (size_t)row*D_ + d0, v, f32);
  float ss = v[0]*v[0]+v[1]*v[1]+v[2]*v[2]+v[3]*v[3];
  float tot = blk_sum(ss, red);
  float r = rsqrtf(tot*(1.f/D_) + 1e-5f);
  const float* mb = m + b*6144;
  float wn[4]; ld4g(nw, d0, wn, f32);
  float o[4];
  #pragma unroll
  for(int j=0;j<4;j++){
    int d = d0+j;
    o[j] = v[j]*r*wn[j]*(1.f+mb[scale_off+d]) + mb[shift_off+d];
  }
  st4(h + (size_t)row*D_ + d0, o);
}

// ---- fused: x2 = x + gate_msa*proj, then h2 = rmsnorm(x2)*(1+scale_mlp)+shift_mlp
__global__ __launch_bounds__(256) void k_resid_rms(const void* x, const u16* y, const float* m,
                                                   const void* nw, float* x2, u16* h,
                                                   const int* flag){
  bool f32 = flag[0] != 0;
  __shared__ float red[4];
  int row = blockIdx.x; int b = row >> 11;
  int d0 = threadIdx.x*4;
  size_t i4 = (size_t)row*D_ + d0;
  float xv[4], yv[4];
  ld4g(x, i4, xv, f32); ld4(y+i4, yv);
  const float* mb = m + b*6144;
  float v[4];
  #pragma unroll
  for(int j=0;j<4;j++) v[j] = xv[j] + mb[2048+d0+j]*yv[j];
  float4 t; t.x=v[0]; t.y=v[1]; t.z=v[2]; t.w=v[3];
  *reinterpret_cast<float4*>(x2+i4) = t;
  float ss = v[0]*v[0]+v[1]*v[1]+v[2]*v[2]+v[3]*v[3];
  float tot = blk_sum(ss, red);
  float r = rsqrtf(tot*(1.f/D_) + 1e-5f);
  float wn[4]; ld4g(nw, d0, wn, f32);
  float o[4];
  #pragma unroll
  for(int j=0;j<4;j++)
    o[j] = v[j]*r*wn[j]*(1.f+mb[4096+d0+j]) + mb[3072+d0+j];
  st4(h + i4, o);
}

// ---- layernorm + RoPE in place over q (y=0) and k (y=1) head slices of fused QKV
__global__ __launch_bounds__(256) void k_ln_rope2(u16* t, const void* qw, const void* qb,
                                                  const void* kw, const void* kb2,
                                                  const void* fc, const void* fs, const int* flag){
  bool f32 = flag[0] != 0;
  __shared__ float red[4];
  int row = blockIdx.x; int s = row & (S_-1);
  const void* w  = blockIdx.y ? kw  : qw;
  const void* bb = blockIdx.y ? kb2 : qb;
  int d0 = threadIdx.x*4;
  u16* tp = t + (size_t)row*3072 + blockIdx.y*1024 + d0;
  float v[4]; ld4(tp, v);
  float sm = v[0]+v[1]+v[2]+v[3];
  float sq = v[0]*v[0]+v[1]*v[1]+v[2]*v[2]+v[3]*v[3];
  float tsm = blk_sum(sm, red);
  float tsq = blk_sum(sq, red);
  float mu  = tsm*(1.f/D_);
  float var = tsq*(1.f/D_) - mu*mu;
  float rs  = rsqrtf(var + 1e-5f);
  float wv[4], bv[4]; ld4g(w, d0, wv, f32); ld4g(bb, d0, bv, f32);
  float y[4];
  #pragma unroll
  for(int j=0;j<4;j++) y[j] = (v[j]-mu)*rs*wv[j] + bv[j];
  int pos = d0 & 63; int i0 = pos>>1;
  float c0 = ld1g(fc, s*32+i0,   f32), s0 = ld1g(fs, s*32+i0,   f32);
  float c1 = ld1g(fc, s*32+i0+1, f32), s1 = ld1g(fs, s*32+i0+1, f32);
  float o[4];
  o[0] = y[0]*c0 - y[1]*s0;
  o[1] = y[0]*s0 + y[1]*c0;
  o[2] = y[2]*c1 - y[3]*s1;
  o[3] = y[2]*s1 + y[3]*c1;
  st4(tp, o);
}

// ---- weight transpose+cast, multi-source: z selects W0/W1/W2; dst offset z*Kd*Nd
__global__ __launch_bounds__(256) void k_wt3(const void* W0, const void* W1, const void* W2,
                                             u16* WT, int Kd, int Nd, const int* flag){
  bool f32 = flag[0] != 0;
  const void* W = blockIdx.z==0 ? W0 : (blockIdx.z==1 ? W1 : W2);
  u16* dst_base = WT + (size_t)blockIdx.z * (size_t)Kd * Nd;
  __shared__ u16 L[64][72];
  int tid = threadIdx.x;
  int k0 = blockIdx.x*64, n0 = blockIdx.y*64;
  int r = tid>>2, c0 = (tid&3)*16;
  if(f32){
    const float* Wf = (const float*)W;
    #pragma unroll
    for(int j=0;j<4;j++){
      float4 t = *reinterpret_cast<const float4*>(&Wf[(size_t)(k0+r)*Nd + n0 + c0 + j*4]);
      L[r][c0+j*4+0]=f2bfr(t.x); L[r][c0+j*4+1]=f2bfr(t.y);
      L[r][c0+j*4+2]=f2bfr(t.z); L[r][c0+j*4+3]=f2bfr(t.w);
    }
  }else{
    const u16* Wh = (const u16*)W;
    *reinterpret_cast<short8*>(&L[r][c0]) =
      *reinterpret_cast<const short8*>(&Wh[(size_t)(k0+r)*Nd + n0 + c0]);
    *reinterpret_cast<short8*>(&L[r][c0+8]) =
      *reinterpret_cast<const short8*>(&Wh[(size_t)(k0+r)*Nd + n0 + c0 + 8]);
  }
  __syncthreads();
  int n = tid>>2, kk0 = (tid&3)*16;
  u16 tmp[16];
  #pragma unroll
  for(int j=0;j<16;j++) tmp[j] = L[kk0+j][n];
  u16* dst = dst_base + (size_t)(n0+n)*Kd + k0 + kk0;
  *reinterpret_cast<short8*>(dst)   = *reinterpret_cast<const short8*>(tmp);
  *reinterpret_cast<short8*>(dst+8) = *reinterpret_cast<const short8*>(tmp+8);
}

// ---- w1/w3 interleaved transpose: w1 col n -> WT row (n>>5)*64+(n&31); w3 -> +32
__global__ __launch_bounds__(256) void k_wt13(const void* W1, const void* W3,
                                              u16* WT, const int* flag){
  bool f32 = flag[0] != 0;
  const int Kd = 1024, Nd = HID_;
  const void* W = blockIdx.z ? W3 : W1;
  int radd = blockIdx.z ? 32 : 0;
  __shared__ u16 L[64][72];
  int tid = threadIdx.x;
  int k0 = blockIdx.x*64, n0 = blockIdx.y*64;
  int r = tid>>2, c0 = (tid&3)*16;
  if(f32){
    const float* Wf = (const float*)W;
    #pragma unroll
    for(int j=0;j<4;j++){
      float4 t = *reinterpret_cast<const float4*>(&Wf[(size_t)(k0+r)*Nd + n0 + c0 + j*4]);
      L[r][c0+j*4+0]=f2bfr(t.x); L[r][c0+j*4+1]=f2bfr(t.y);
      L[r][c0+j*4+2]=f2bfr(t.z); L[r][c0+j*4+3]=f2bfr(t.w);
    }
  }else{
    const u16* Wh = (const u16*)W;
    *reinterpret_cast<short8*>(&L[r][c0]) =
      *reinterpret_cast<const short8*>(&Wh[(size_t)(k0+r)*Nd + n0 + c0]);
    *reinterpret_cast<short8*>(&L[r][c0+8]) =
      *reinterpret_cast<const short8*>(&Wh[(size_t)(k0+r)*Nd + n0 + c0 + 8]);
  }
  __syncthreads();
  int n = tid>>2, kk0 = (tid&3)*16;
  u16 tmp[16];
  #pragma unroll
  for(int j=0;j<16;j++) tmp[j] = L[kk0+j][n];
  int nglob = n0 + n;
  int rw = ((nglob>>5)<<6) + (nglob&31) + radd;
  u16* dst = WT + (size_t)rw*Kd + k0 + kk0;
  *reinterpret_cast<short8*>(dst)   = *reinterpret_cast<const short8*>(tmp);
  *reinterpret_cast<short8*>(dst+8) = *reinterpret_cast<const short8*>(tmp+8);
}

// ---- MFMA GEMM, XOR-swizzled LDS, ping-pong double-buffer, bijective XCD-chunk
// block swizzle (y-fastest: each XCD owns a contiguous B-column chunk, resident
// in its L2 across all M-panels). EPI: 0=plain bf16 C, 1=silu-pair -> g[.][2816],
// 2=residual -> d_out (reads x2, gate).
template<int TM, int EPI>
__global__ __launch_bounds__(256) void k_gemm_mfma(const u16* A, int lda, const u16* BT, int ldb,
                                                   u16* C, int N, int K,
                                                   const float* x2, const float* mg,
                                                   void* outp, const int* flag){
  __shared__ __align__(16) u16 As[2][TM*64];
  __shared__ __align__(16) u16 Bs[2][128*64];
  int tid = threadIdx.x, lane = tid&63, w = tid>>6;
  int col = lane&15, quad = lane>>4;
  // XCD-chunk swizzle (m204 bijective): hw block bid -> logical lin, decomposed
  // y-fastest so one XCD's blocks share a B-column chunk (<4MB, L2-resident).
  int gx = gridDim.x, gy = gridDim.y;
  int nwg = gx*gy;
  int bid = blockIdx.y*gx + blockIdx.x;
  int xcd = bid & 7, pos = bid >> 3;
  int q = nwg >> 3, r8 = nwg & 7;
  int lin = (xcd < r8 ? xcd*(q+1) : r8*(q+1) + (xcd-r8)*q) + pos;
  int bx = lin / gy, by = lin - bx*gy;
  int row0 = by*TM, col0 = bx*128;
  const u16* Ab = A  + (size_t)row0*lda;
  const u16* Bb = BT + (size_t)col0*ldb;
  constexpr int MI = TM/32;
  int wm = (w>>1)*(TM/2);
  int wn = (w&1)*64;
  f32x4 acc[MI][4];
  #pragma unroll
  for(int i=0;i<MI;i++)
    #pragma unroll
    for(int j=0;j<4;j++) acc[i][j] = (f32x4){0.f,0.f,0.f,0.f};

  const int T = K/64;
  // prologue: tile 0 -> buf 0
  {
    #pragma unroll
    for(int i=0;i<TM/32;i++){
      int c = i*256 + w*64 + lane;
      int r = c>>3, s = c&7, gs = s ^ (r&7);
      gl2lds16(Ab + (size_t)r*lda + gs*8, &As[0][0] + (size_t)c*8);
    }
    #pragma unroll
    for(int i=0;i<4;i++){
      int c = i*256 + w*64 + lane;
      int r = c>>3, s = c&7, gs = s ^ (r&7);
      gl2lds16(Bb + (size_t)r*ldb + gs*8, &Bs[0][0] + (size_t)c*8);
    }
  }
  __syncthreads();

  for(int t=0;t<T;t++){
    // prefetch tile t+1 into the other buffer (overlaps with compute below)
    if(t+1 < T){
      int k0 = (t+1)*64, b = (t+1)&1;
      #pragma unroll
      for(int i=0;i<TM/32;i++){
        int c = i*256 + w*64 + lane;
        int r = c>>3, s = c&7, gs = s ^ (r&7);
        gl2lds16(Ab + (size_t)r*lda + k0 + gs*8, &As[b][0] + (size_t)c*8);
      }
      #pragma unroll
      for(int i=0;i<4;i++){
        int c = i*256 + w*64 + lane;
        int r = c>>3, s = c&7, gs = s ^ (r&7);
        gl2lds16(Bb + (size_t)r*ldb + k0 + gs*8, &Bs[b][0] + (size_t)c*8);
      }
    }
    const u16* Ac = &As[t&1][0];
    const u16* Bc = &Bs[t&1][0];
    #pragma unroll
    for(int ks=0;ks<64;ks+=32){
      short8 af[MI], bfr[4];
      #pragma unroll
      for(int mi=0;mi<MI;mi++){
        int r = wm+mi*16+col;
        int sch = ((ks>>3) + quad) ^ (col&7);
        af[mi] = *reinterpret_cast<const short8*>(&Ac[r*64 + sch*8]);
      }
      #pragma unroll
      for(int ni=0;ni<4;ni++){
        int r = wn+ni*16+col;
        int sch = ((ks>>3) + quad) ^ (col&7);
        bfr[ni] = *reinterpret_cast<const short8*>(&Bc[r*64 + sch*8]);
      }
      #pragma unroll
      for(int mi=0;mi<MI;mi++)
        #pragma unroll
        for(int ni=0;ni<4;ni++)
          acc[mi][ni] = __builtin_amdgcn_mfma_f32_16x16x32_bf16(af[mi], bfr[ni], acc[mi][ni], 0,0,0);
    }
    // implicit s_waitcnt vmcnt(0) lgkmcnt(0) before s_barrier drains the
    // prefetch (which had the whole compute phase to land) and fences reads.
    __syncthreads();
  }
  if constexpr(EPI==0){
    #pragma unroll
    for(int mi=0;mi<MI;mi++)
      #pragma unroll
      for(int r=0;r<4;r++){
        size_t rowoff = (size_t)(row0+wm+mi*16+quad*4+r)*N + col0 + wn;
        #pragma unroll
        for(int ni=0;ni<4;ni++)
          C[rowoff + ni*16 + col] = f2bfr(acc[mi][ni][r]);
      }
  } else if constexpr(EPI==1){
    // acc[mi][0..1] = h1 cols, acc[mi][2..3] = matching h3 cols
    int cb = bx*64 + (wn?32:0) + col;
    #pragma unroll
    for(int mi=0;mi<MI;mi++)
      #pragma unroll
      for(int r=0;r<4;r++){
        int row = row0+wm+mi*16+quad*4+r;
        u16* gp = C + (size_t)row*HID_ + cb;
        #pragma unroll
        for(int ni=0;ni<2;ni++){
          float a = acc[mi][ni][r], cc = acc[mi][ni+2][r];
          float sv = a * __builtin_amdgcn_rcpf(1.f + __builtin_amdgcn_exp2f(-1.4426950f*a));
          gp[ni*16] = f2bfr(sv*cc);
        }
      }
  } else {
    bool f32o = flag[0] != 0;
    #pragma unroll
    for(int mi=0;mi<MI;mi++)
      #pragma unroll
      for(int r=0;r<4;r++){
        int row = row0+wm+mi*16+quad*4+r;
        int b = row >> 11;
        #pragma unroll
        for(int ni=0;ni<4;ni++){
          int cc = col0 + wn + ni*16 + col;
          float v = x2[(size_t)row*D_ + cc] + mg[b*6144 + 5120 + cc]*acc[mi][ni][r];
          if(f32o) ((float*)outp)[(size_t)row*D_ + cc] = v;
          else     ((u16*)outp)[(size_t)row*D_ + cc]   = f2bfr(v);
        }
      }
  }
}

// ---- V transpose: vt[(b*H+h)][hd][key] <- v[(b*S+key)*vstr + h*64+hd]
__global__ __launch_bounds__(256) void k_vt(const u16* v, int vstr, u16* vt){
  __shared__ u16 L[64][72];
  int tid = threadIdx.x;
  int wg = blockIdx.x;
  int kblk = wg & 31; int bh = wg >> 5; int h = bh & 15, b = bh >> 4;
  int row = tid>>2, c0 = (tid&3)*16;
  const u16* src = v + (size_t)(b*S_ + kblk*64 + row)*vstr + h*HD_ + c0;
  *reinterpret_cast<short8*>(&L[row][c0])   = *reinterpret_cast<const short8*>(src);
  *reinterpret_cast<short8*>(&L[row][c0+8]) = *reinterpret_cast<const short8*>(src+8);
  __syncthreads();
  int hd = tid>>2, k0 = (tid&3)*16;
  u16 tmp[16];
  #pragma unroll
  for(int j=0;j<16;j++) tmp[j] = L[k0+j][hd];
  u16* dst = vt + ((size_t)bh*HD_ + hd)*S_ + kblk*64 + k0;
  *reinterpret_cast<short8*>(dst)   = *reinterpret_cast<const short8*>(tmp);
  *reinterpret_cast<short8*>(dst+8) = *reinterpret_cast<const short8*>(tmp+8);
}

// ---- MFMA flash attention v7: 2 q-groups per wave (32 q-rows/wave): each ka/vf
// LDS read feeds 2 MFMAs, 2 independent softmax chains give in-wave ILP.
// s_setprio(1) around MFMA clusters (T5); XCD swizzle; ones-row l-sum; defer-max.
__global__ __launch_bounds__(256, 2) void k_attn_mfma(const u16* q, const u16* k, const u16* vt,
                                                      u16* o, int qks){
  __shared__ __align__(16) u16 Ks[2][64*64];
  __shared__ __align__(16) u16 Vs[2][64*64];
  int tid = threadIdx.x, lane = tid & 63, wid = tid >> 6;
  int col = lane & 15, quad = lane >> 4;
  int c7 = col & 7;
  // bijective XCD swizzle: 512 blocks = 8 XCDs x 64; same-(b,h) q-blocks stay on
  // one XCD so its K/V panel stays in that XCD's L2 (4 panels x 512KB < 4MB).
  int wg = ((blockIdx.x & 7) << 6) + (blockIdx.x >> 3);
  int qb = wg & 15; int bh = wg >> 4; int h = bh & 15, b = bh >> 4;

  const u16* kb  = k  + (size_t)b*S_*qks + h*HD_;
  const u16* vtb = vt + (size_t)bh*HD_*S_;

  short8 qa[2][2];   // [group][khalf]; Q pre-scaled by 0.125*log2(e)
  {
    const float qscale = 0.18033688f;
    const u16* qp = q + (size_t)(b*S_ + qb*128 + wid*16 + col)*qks + h*HD_ + quad*8;
    #pragma unroll
    for(int g=0;g<2;g++){
      short8 t0 = *reinterpret_cast<const short8*>(qp + (size_t)g*64*qks);
      short8 t1 = *reinterpret_cast<const short8*>(qp + (size_t)g*64*qks + 32);
      #pragma unroll
      for(int j=0;j<8;j++){
        qa[g][0][j] = (short)f2bf(bf2f((u16)t0[j])*qscale);
        qa[g][1][j] = (short)f2bf(bf2f((u16)t1[j])*qscale);
      }
    }
  }
  short8 vone;      // bf16 1.0 splat: A-operand of ones for the l-sum MFMA
  #pragma unroll
  for(int j=0;j<8;j++) vone[j] = (short)0x3F80;

  float m_i[2] = {-1e30f, -1e30f};
  f32x2 nm[2]; nm[0] = (f32x2){1e30f,1e30f}; nm[1] = (f32x2){1e30f,1e30f};
  f32x4 accl[2];
  accl[0] = (f32x4){0.f,0.f,0.f,0.f}; accl[1] = (f32x4){0.f,0.f,0.f,0.f};
  f32x4 acc[2][4];
  #pragma unroll
  for(int g=0;g<2;g++)
    #pragma unroll
    for(int t=0;t<4;t++) acc[g][t] = (f32x4){0.f,0.f,0.f,0.f};

  // staging: lds row l holds K global row kl(l) (MFMA permutation), with 16B
  // slot s of the row stored swizzled: LDS(l, s) = src(l)[s ^ (l&7)].
  // Linear LDS dest (= uniform + lane*16B) keeps global_load_lds legal.
  int l0 = tid>>3;        // lds row, chunk half 0
  int l1 = 32 + l0;       // chunk half 1 (l1&7 == l0&7)
  int gs = ((tid&7) ^ (l0&7))*8;   // swizzled source slot offset (u16)
  int kl0 = 32*(l0>>5) + 8*((l0>>2)&3) + 4*((l0>>4)&1) + (l0&3);
  int kl1 = 32*(l1>>5) + 8*((l1>>2)&3) + 4*((l1>>4)&1) + (l1&3);
  const u16* kp0 = kb + (size_t)kl0*qks + gs;
  const u16* kp1 = kb + (size_t)kl1*qks + gs;
  const u16* vp0 = vtb + (size_t)l0*S_ + gs;
  const u16* vp1 = vtb + (size_t)l1*S_ + gs;

  // prologue: stage chunk 0 into buf 0
  gl2lds16(kp0, &Ks[0][tid*8]);
  gl2lds16(kp1, &Ks[0][2048 + tid*8]);
  gl2lds16(vp0, &Vs[0][tid*8]);
  gl2lds16(vp1, &Vs[0][2048 + tid*8]);

  for(int i=0;i<32;i++){
    __syncthreads();
    const u16* Kc = Ks[i&1];
    const u16* Vc = Vs[i&1];
    if(i < 31){
      size_t off = (size_t)(i+1)*64;
      u16* Kn = (u16*)Ks[(i+1)&1];
      u16* Vn = (u16*)Vs[(i+1)&1];
      gl2lds16(kp0 + off*qks, &Kn[tid*8]);
      gl2lds16(kp1 + off*qks, &Kn[2048 + tid*8]);
      gl2lds16(vp0 + off,     &Vn[tid*8]);
      gl2lds16(vp1 + off,     &Vn[2048 + tid*8]);
    }

    f32x4 st[2][4];
    __builtin_amdgcn_s_setprio(1);
    #pragma unroll
    for(int mt=0;mt<4;mt++){
      short8 ka0 = *reinterpret_cast<const short8*>(&Kc[(mt*16+col)*64 + ((quad  ) ^ c7)*8]);
      short8 ka1 = *reinterpret_cast<const short8*>(&Kc[(mt*16+col)*64 + ((quad+4) ^ c7)*8]);
      f32x4 z = (f32x4){0.f,0.f,0.f,0.f};
      st[0][mt] = __builtin_amdgcn_mfma_f32_16x16x32_bf16(ka0, qa[0][0], z, 0,0,0);
      st[1][mt] = __builtin_amdgcn_mfma_f32_16x16x32_bf16(ka0, qa[1][0], z, 0,0,0);
      st[0][mt] = __builtin_amdgcn_mfma_f32_16x16x32_bf16(ka1, qa[0][1], st[0][mt], 0,0,0);
      st[1][mt] = __builtin_amdgcn_mfma_f32_16x16x32_bf16(ka1, qa[1][1], st[1][mt], 0,0,0);
    }
    __builtin_amdgcn_s_setprio(0);

    u32x4 pws[2][2];
    #pragma unroll
    for(int g=0;g<2;g++){
      // row max: v_max3 tree + permlane cross-quad combine (VALU only)
      float t0 = vmax3(st[g][0][0], st[g][0][1], st[g][0][2]);
      float t1 = vmax3(st[g][0][3], st[g][1][0], st[g][1][1]);
      float t2 = vmax3(st[g][1][2], st[g][1][3], st[g][2][0]);
      float t3 = vmax3(st[g][2][1], st[g][2][2], st[g][2][3]);
      float t4 = vmax3(st[g][3][0], st[g][3][1], st[g][3][2]);
      float cm = fmaxf(vmax3(t0, t1, t2), vmax3(t3, t4, st[g][3][3]));
      { float a, bb2; plswap16(cm, a, bb2); cm = fmaxf(a, bb2);
        plswap32(cm, a, bb2); cm = fmaxf(a, bb2); }
      // defer-max: rescale only when the max grew by >8 (P bounded by 2^8)
      if(__any(cm - m_i[g] > 8.f)){
        float mn = fmaxf(m_i[g], cm);
        float al = __builtin_amdgcn_exp2f(m_i[g] - mn);
        m_i[g] = mn;
        nm[g] = (f32x2){-mn, -mn};
        accl[g][0] *= al;
        #pragma unroll
        for(int t=0;t<4;t++) acc[g][t] *= al;
      }
      float pe[4][4];
      #pragma unroll
      for(int mt=0;mt<4;mt++){
        f32x2 lo = pkadd(st[g][mt].xy, nm[g]);
        f32x2 hi = pkadd(st[g][mt].zw, nm[g]);
        pe[mt][0] = __builtin_amdgcn_exp2f(lo.x);
        pe[mt][1] = __builtin_amdgcn_exp2f(lo.y);
        pe[mt][2] = __builtin_amdgcn_exp2f(hi.x);
        pe[mt][3] = __builtin_amdgcn_exp2f(hi.y);
      }
      #pragma unroll
      for(int w=0;w<2;w++){
        pws[g][w][0] = cvtpk(pe[2*w][0],   pe[2*w][1]);
        pws[g][w][1] = cvtpk(pe[2*w][2],   pe[2*w][3]);
        pws[g][w][2] = cvtpk(pe[2*w+1][0], pe[2*w+1][1]);
        pws[g][w][3] = cvtpk(pe[2*w+1][2], pe[2*w+1][3]);
      }
    }

    // PV + l-sum on the matrix pipe; each vf read feeds both q-groups
    __builtin_amdgcn_s_setprio(1);
    #pragma unroll
    for(int w=0;w<2;w++){
      short8 pb0 = *reinterpret_cast<short8*>(&pws[0][w]);
      short8 pb1 = *reinterpret_cast<short8*>(&pws[1][w]);
      #pragma unroll
      for(int ht=0;ht<4;ht++){
        short8 vf = *reinterpret_cast<const short8*>(&Vc[(ht*16+col)*64 + ((w*4+quad) ^ c7)*8]);
        acc[0][ht] = __builtin_amdgcn_mfma_f32_16x16x32_bf16(vf, pb0, acc[0][ht], 0,0,0);
        acc[1][ht] = __builtin_amdgcn_mfma_f32_16x16x32_bf16(vf, pb1, acc[1][ht], 0,0,0);
      }
      accl[0] = __builtin_amdgcn_mfma_f32_16x16x32_bf16(vone, pb0, accl[0], 0,0,0);
      accl[1] = __builtin_amdgcn_mfma_f32_16x16x32_bf16(vone, pb1, accl[1], 0,0,0);
    }
    __builtin_amdgcn_s_setprio(0);
  }
  // accl[g][0] is the lane's full denominator (D rows all equal sum_k P[k][col])
  #pragma unroll
  for(int g=0;g<2;g++){
    float inv = __builtin_amdgcn_rcpf(accl[g][0]);
    u16* ob = o + (size_t)(b*S_ + qb*128 + g*64 + wid*16 + col)*D_ + h*HD_;
    #pragma unroll
    for(int ht=0;ht<4;ht++){
      uint2 t;
      t.x = cvtpk(acc[g][ht][0]*inv, acc[g][ht][1]*inv);
      t.y = cvtpk(acc[g][ht][2]*inv, acc[g][ht][3]*inv);
      *reinterpret_cast<uint2*>(ob + ht*16 + quad*4) = t;
    }
  }
}

extern "C" void kernel_launch(void* const* d_in, const int* in_sizes, int n_in,
                              void* d_out, int out_size, void* d_ws, size_t ws_size,
                              hipStream_t stream){
  const void* x   = d_in[0];
  const void* ada = d_in[1];
  const void* fc  = d_in[2];
  const void* fs  = d_in[3];
  const void* wq  = d_in[4];
  const void* wk  = d_in[5];
  const void* wv  = d_in[6];
  const void* wo  = d_in[7];
  const void* qnw = d_in[8];
  const void* qnb = d_in[9];
  const void* knw = d_in[10];
  const void* knb = d_in[11];
  const void* anw = d_in[12];
  const void* fnw = d_in[13];
  const void* aw  = d_in[14];
  const void* ab  = d_in[15];
  const void* w1  = d_in[16];
  const void* w2  = d_in[17];
  const void* w3  = d_in[18];
  char* ws = (char*)d_ws;
  const size_t MB = 1u<<20;

  int*   flag = (int*)ws;
  float* m    = (float*)(ws + 4096);
  u16*  hbuf  = (u16*)(ws + 1*MB);     // h -> attn-out -> h2 (8MB)
  u16*  xqkv  = (u16*)(ws + 9*MB);     // [4096][3072] (24MB); dead after attn
  float* x2   = (float*)(ws + 9*MB);   // fp32 residual (16MB), aliases xqkv
  u16*  proj  = (u16*)(ws + 25*MB);    // proj (8MB), aliases xqkv tail
  u16*  wreg  = (u16*)(ws + 33*MB);    // 12MB: wqkvT -> vt -> wtoT -> wt13T -> w2T
  u16*  g     = (u16*)(ws + 45*MB);    // [4096][2816] (22MB) -> ends 67MB
  u16*  vt    = wreg;

  dim3 blk(256);

  k_probe_zero<<<dim3(48), blk, 0, stream>>>((const u16*)fc, flag, m);
  k_adaln<<<dim3(24,8), blk, 0, stream>>>(ada, aw, ab, m, flag);
  k_rms_mod<<<dim3(B_*S_), blk, 0, stream>>>(x, anw, m, hbuf, 0, 1024, flag);

  // fused QKV
  k_wt3<<<dim3(16,16,3), blk, 0, stream>>>(wq, wk, wv, wreg, 1024, 1024, flag);
  k_gemm_mfma<128,0><<<dim3(24,32), blk, 0, stream>>>(hbuf, 1024, wreg, 1024, xqkv,
                                                      3072, 1024, nullptr, nullptr, nullptr, flag);

  k_ln_rope2<<<dim3(B_*S_,2), blk, 0, stream>>>(xqkv, qnw, qnb, knw, knb, fc, fs, flag);
  k_vt<<<dim3(B_*H_*S_/64), blk, 0, stream>>>(xqkv + 2048, 3072, vt);
  k_attn_mfma<<<dim3(B_*H_*S_/128), blk, 0, stream>>>(xqkv, xqkv + 1024, vt, hbuf, 3072);

  k_wt3<<<dim3(16,16,1), blk, 0, stream>>>(wo, wo, wo, wreg, 1024, 1024, flag);
  k_gemm_mfma<128,0><<<dim3(8,32), blk, 0, stream>>>(hbuf, 1024, wreg, 1024, proj,
                                                     1024, 1024, nullptr, nullptr, nullptr, flag);
  k_resid_rms<<<dim3(B_*S_), blk, 0, stream>>>(x, proj, m, fnw, x2, hbuf, flag);

  // fused w1|w3 with silu epilogue -> g
  k_wt13<<<dim3(16,44,2), blk, 0, stream>>>(w1, w3, wreg, flag);
  k_gemm_mfma<128,1><<<dim3(44,32), blk, 0, stream>>>(hbuf, 1024, wreg, 1024, g,
                                                      5632, 1024, nullptr, nullptr, nullptr, flag);
  // w2 with fused residual epilogue -> d_out
  k_wt3<<<dim3(44,16,1), blk, 0, stream>>>(w2, w2, w2, wreg, 2816, 1024, flag);
  k_gemm_mfma<128,2><<<dim3(8,32), blk, 0, stream>>>(g, 2816, wreg, 2816, nullptr,
                                                     1024, 2816, x2, m, d_out, flag);
}

// Round 7
// 389.500 us; speedup vs baseline: 1.0952x; 1.0952x over previous
//
#include <hip/hip_runtime.h>
#include <hip/hip_bf16.h>

#define B_   2
#define S_   2048
#define D_   1024
#define H_   16
#define HD_  64
#define HID_ 2816

typedef unsigned short u16;
typedef unsigned int   u32;
typedef __attribute__((ext_vector_type(8))) short short8;
typedef __attribute__((ext_vector_type(4))) float f32x4;
typedef __attribute__((ext_vector_type(2))) float f32x2;
typedef __attribute__((ext_vector_type(4))) u32   u32x4;
typedef __attribute__((ext_vector_type(2))) unsigned uvec2;

static __device__ __forceinline__ float bf2f(u16 u){ return __uint_as_float(((u32)u)<<16); }
static __device__ __forceinline__ u16 f2bf(float f){
  u32 u = __float_as_uint(f);
  u32 r = (u + 0x7FFFu + ((u>>16)&1u)) >> 16;   // round-to-nearest-even
  return (u16)r;
}
// round-half-up bf16 (2 ops)
static __device__ __forceinline__ u16 f2bfr(float f){
  return (u16)((__float_as_uint(f) + 0x8000u) >> 16);
}
// single-instruction packed f32->bf16 pair (lo, hi)
static __device__ __forceinline__ u32 cvtpk(float lo, float hi){
  u32 r; asm("v_cvt_pk_bf16_f32 %0, %1, %2" : "=v"(r) : "v"(lo), "v"(hi)); return r;
}
static __device__ __forceinline__ float vmax3(float a, float b, float c){
  float d; asm("v_max3_f32 %0, %1, %2, %3" : "=v"(d) : "v"(a), "v"(b), "v"(c)); return d;
}
// packed dual-f32 add (VOP3P, CDNA2+)
static __device__ __forceinline__ f32x2 pkadd(f32x2 a, f32x2 b){
  f32x2 d; asm("v_pk_add_f32 %0, %1, %2" : "=v"(d) : "v"(a), "v"(b)); return d;
}
// cross-lane pair exchange via permlane swaps (VALU, no DS pipe).
static __device__ __forceinline__ void plswap16(float x, float& a, float& b){
#if __has_builtin(__builtin_amdgcn_permlane16_swap)
  uvec2 r = __builtin_amdgcn_permlane16_swap(__float_as_uint(x), __float_as_uint(x), false, false);
  a = __uint_as_float(r[0]); b = __uint_as_float(r[1]);
#else
  a = x; b = __shfl_xor(x, 16, 64);
#endif
}
static __device__ __forceinline__ void plswap32(float x, float& a, float& b){
#if __has_builtin(__builtin_amdgcn_permlane32_swap)
  uvec2 r = __builtin_amdgcn_permlane32_swap(__float_as_uint(x), __float_as_uint(x), false, false);
  a = __uint_as_float(r[0]); b = __uint_as_float(r[1]);
#else
  a = x; b = __shfl_xor(x, 32, 64);
#endif
}

static __device__ __forceinline__ void ld4(const u16* p, float* v){
  ushort4 t = *reinterpret_cast<const ushort4*>(p);
  v[0]=bf2f(t.x); v[1]=bf2f(t.y); v[2]=bf2f(t.z); v[3]=bf2f(t.w);
}
static __device__ __forceinline__ void st4(u16* p, const float* v){
  ushort4 t; t.x=f2bf(v[0]); t.y=f2bf(v[1]); t.z=f2bf(v[2]); t.w=f2bf(v[3]);
  *reinterpret_cast<ushort4*>(p)=t;
}

static __device__ __forceinline__ float ld1g(const void* p, size_t i, bool f32){
  return f32 ? ((const float*)p)[i] : bf2f(((const u16*)p)[i]);
}
static __device__ __forceinline__ void ld4g(const void* p, size_t i, float* v, bool f32){
  if(f32){
    float4 t = *reinterpret_cast<const float4*>((const float*)p + i);
    v[0]=t.x; v[1]=t.y; v[2]=t.z; v[3]=t.w;
  }else{
    ushort4 t = *reinterpret_cast<const ushort4*>((const u16*)p + i);
    v[0]=bf2f(t.x); v[1]=bf2f(t.y); v[2]=bf2f(t.z); v[3]=bf2f(t.w);
  }
}

// async global->LDS, 16B per lane
static __device__ __forceinline__ void gl2lds16(const u16* g, const u16* l){
  typedef __attribute__((address_space(3))) u16 lds_u16;
  typedef const __attribute__((address_space(1))) u16 glb_u16;
  __builtin_amdgcn_global_load_lds((glb_u16*)(uintptr_t)g,
                                   (lds_u16*)(u32)(uintptr_t)l, 16, 0, 0);
}

// dtype probe: freqs_cos[0]==1.0f -> if fp32, low u16 of first word is 0.
static __device__ __forceinline__ bool is_f32(const u16* fcp){ return fcp[0] == 0; }

static __device__ __forceinline__ float blk_sum(float v, float* red){
  #pragma unroll
  for(int o=32;o;o>>=1) v += __shfl_xor(v,o,64);
  int lane = threadIdx.x & 63, w = threadIdx.x >> 6;
  if(lane==0) red[w]=v;
  __syncthreads();
  float t = red[0]+red[1]+red[2]+red[3];
  __syncthreads();
  return t;
}

// ---- mega weight-transpose kernel: all 7 weight matrices in ONE launch, plus
// zeroing of m. Segments (1D grid, 3184 blocks):
//   [0,48)      zero m
//   [48,816)    wq/wk/wv -> qkvT      (z=seg/256; 16x16 tiles, Kd=Nd=1024)
//   [816,1072)  wo -> woT             (16x16)
//   [1072,2480) w1/w3 -> w13T interleaved rows (z=seg/704; 16x44, Nd=2816)
//   [2480,3184) w2 -> w2T             (44x16, Kd=2816, Nd=1024)
__global__ __launch_bounds__(256) void k_wtall(const void* wq, const void* wk, const void* wv,
                                               const void* wo_, const void* w1, const void* w3,
                                               const void* w2_,
                                               u16* qkvT, u16* woT, u16* w13T, u16* w2T,
                                               const u16* fcp, float* m){
  int bid = blockIdx.x;
  if(bid < 48){
    int i = bid*256 + threadIdx.x;
    if(i < 12288) m[i] = 0.f;
    return;
  }
  bid -= 48;
  bool f32 = is_f32(fcp);
  const void* W; u16* dst_base; int Kd, Nd, k0, n0, mode;  // mode: 0 linear, 1/2 w13 interleave
  if(bid < 768){
    int z = bid >> 8, rem = bid & 255;
    W = z==0 ? wq : (z==1 ? wk : wv);
    dst_base = qkvT + (size_t)z*1024*1024;
    Kd = 1024; Nd = 1024; k0 = (rem&15)*64; n0 = (rem>>4)*64; mode = 0;
  } else if(bid < 1024){
    int rem = bid - 768;
    W = wo_; dst_base = woT;
    Kd = 1024; Nd = 1024; k0 = (rem&15)*64; n0 = (rem>>4)*64; mode = 0;
  } else if(bid < 2432){
    int z = (bid-1024)/704, rem = (bid-1024) - z*704;
    W = z ? w3 : w1; dst_base = w13T;
    Kd = 1024; Nd = HID_; k0 = (rem&15)*64; n0 = (rem>>4)*64; mode = z ? 2 : 1;
  } else {
    int rem = bid - 2432;
    W = w2_; dst_base = w2T;
    Kd = 2816; Nd = 1024;
    int kb = rem % 44, nb = rem / 44;
    k0 = kb*64; n0 = nb*64; mode = 0;
  }
  __shared__ u16 L[64][72];
  int tid = threadIdx.x;
  int r = tid>>2, c0 = (tid&3)*16;
  if(f32){
    const float* Wf = (const float*)W;
    #pragma unroll
    for(int j=0;j<4;j++){
      float4 t = *reinterpret_cast<const float4*>(&Wf[(size_t)(k0+r)*Nd + n0 + c0 + j*4]);
      L[r][c0+j*4+0]=f2bfr(t.x); L[r][c0+j*4+1]=f2bfr(t.y);
      L[r][c0+j*4+2]=f2bfr(t.z); L[r][c0+j*4+3]=f2bfr(t.w);
    }
  }else{
    const u16* Wh = (const u16*)W;
    *reinterpret_cast<short8*>(&L[r][c0]) =
      *reinterpret_cast<const short8*>(&Wh[(size_t)(k0+r)*Nd + n0 + c0]);
    *reinterpret_cast<short8*>(&L[r][c0+8]) =
      *reinterpret_cast<const short8*>(&Wh[(size_t)(k0+r)*Nd + n0 + c0 + 8]);
  }
  __syncthreads();
  int n = tid>>2, kk0 = (tid&3)*16;
  u16 tmp[16];
  #pragma unroll
  for(int j=0;j<16;j++) tmp[j] = L[kk0+j][n];
  int nglob = n0 + n;
  int rw = (mode==0) ? nglob : ((nglob>>5)<<6) + (nglob&31) + (mode==2 ? 32 : 0);
  u16* dst = dst_base + (size_t)rw*Kd + k0 + kk0;
  *reinterpret_cast<short8*>(dst)   = *reinterpret_cast<const short8*>(tmp);
  *reinterpret_cast<short8*>(dst+8) = *reinterpret_cast<const short8*>(tmp+8);
}

// ---- adaLN: m[b][n] = silu(a[b]) . ada_w[:,n] + ada_b[n]
__global__ __launch_bounds__(256) void k_adaln(const void* a, const void* W, const void* bias,
                                               float* m, const u16* fcp){
  bool f32 = is_f32(fcp);
  __shared__ float sl[2][128];
  int bk = blockIdx.y;
  {
    int bb = threadIdx.x >> 7, kk = threadIdx.x & 127;
    float x = ld1g(a, bb*D_ + bk*128 + kk, f32);
    sl[bb][kk] = x/(1.f+__expf(-x));
  }
  __syncthreads();
  int n = blockIdx.x*256 + threadIdx.x;
  float p0 = 0.f, p1 = 0.f;
  for(int kk=0;kk<128;kk++){
    float w = ld1g(W, (size_t)(bk*128+kk)*6144 + n, f32);
    p0 += sl[0][kk]*w; p1 += sl[1][kk]*w;
  }
  if(bk==0){ float bv = ld1g(bias, n, f32); p0 += bv; p1 += bv; }
  atomicAdd(&m[n], p0);
  atomicAdd(&m[6144+n], p1);
}

__global__ __launch_bounds__(256) void k_rms_mod(const void* x, const void* nw, const float* m,
                                                 u16* h, int shift_off, int scale_off,
                                                 const u16* fcp){
  bool f32 = is_f32(fcp);
  __shared__ float red[4];
  int row = blockIdx.x; int b = row >> 11;
  int d0 = threadIdx.x*4;
  float v[4]; ld4g(x, (size_t)row*D_ + d0, v, f32);
  float ss = v[0]*v[0]+v[1]*v[1]+v[2]*v[2]+v[3]*v[3];
  float tot = blk_sum(ss, red);
  float r = rsqrtf(tot*(1.f/D_) + 1e-5f);
  const float* mb = m + b*6144;
  float wn[4]; ld4g(nw, d0, wn, f32);
  float o[4];
  #pragma unroll
  for(int j=0;j<4;j++){
    int d = d0+j;
    o[j] = v[j]*r*wn[j]*(1.f+mb[scale_off+d]) + mb[shift_off+d];
  }
  st4(h + (size_t)row*D_ + d0, o);
}

// ---- fused: x2 = x + gate_msa*proj, then h2 = rmsnorm(x2)*(1+scale_mlp)+shift_mlp
__global__ __launch_bounds__(256) void k_resid_rms(const void* x, const u16* y, const float* m,
                                                   const void* nw, float* x2, u16* h,
                                                   const u16* fcp){
  bool f32 = is_f32(fcp);
  __shared__ float red[4];
  int row = blockIdx.x; int b = row >> 11;
  int d0 = threadIdx.x*4;
  size_t i4 = (size_t)row*D_ + d0;
  float xv[4], yv[4];
  ld4g(x, i4, xv, f32); ld4(y+i4, yv);
  const float* mb = m + b*6144;
  float v[4];
  #pragma unroll
  for(int j=0;j<4;j++) v[j] = xv[j] + mb[2048+d0+j]*yv[j];
  float4 t; t.x=v[0]; t.y=v[1]; t.z=v[2]; t.w=v[3];
  *reinterpret_cast<float4*>(x2+i4) = t;
  float ss = v[0]*v[0]+v[1]*v[1]+v[2]*v[2]+v[3]*v[3];
  float tot = blk_sum(ss, red);
  float r = rsqrtf(tot*(1.f/D_) + 1e-5f);
  float wn[4]; ld4g(nw, d0, wn, f32);
  float o[4];
  #pragma unroll
  for(int j=0;j<4;j++)
    o[j] = v[j]*r*wn[j]*(1.f+mb[4096+d0+j]) + mb[3072+d0+j];
  st4(h + i4, o);
}

// ---- layernorm + RoPE in place over q (y=0) and k (y=1) head slices of fused QKV
__global__ __launch_bounds__(256) void k_ln_rope2(u16* t, const void* qw, const void* qb,
                                                  const void* kw, const void* kb2,
                                                  const void* fc, const void* fs){
  bool f32 = is_f32((const u16*)fc);
  __shared__ float red[4];
  int row = blockIdx.x; int s = row & (S_-1);
  const void* w  = blockIdx.y ? kw  : qw;
  const void* bb = blockIdx.y ? kb2 : qb;
  int d0 = threadIdx.x*4;
  u16* tp = t + (size_t)row*3072 + blockIdx.y*1024 + d0;
  float v[4]; ld4(tp, v);
  float sm = v[0]+v[1]+v[2]+v[3];
  float sq = v[0]*v[0]+v[1]*v[1]+v[2]*v[2]+v[3]*v[3];
  float tsm = blk_sum(sm, red);
  float tsq = blk_sum(sq, red);
  float mu  = tsm*(1.f/D_);
  float var = tsq*(1.f/D_) - mu*mu;
  float rs  = rsqrtf(var + 1e-5f);
  float wv[4], bv[4]; ld4g(w, d0, wv, f32); ld4g(bb, d0, bv, f32);
  float y[4];
  #pragma unroll
  for(int j=0;j<4;j++) y[j] = (v[j]-mu)*rs*wv[j] + bv[j];
  int pos = d0 & 63; int i0 = pos>>1;
  float c0 = ld1g(fc, s*32+i0,   f32), s0 = ld1g(fs, s*32+i0,   f32);
  float c1 = ld1g(fc, s*32+i0+1, f32), s1 = ld1g(fs, s*32+i0+1, f32);
  float o[4];
  o[0] = y[0]*c0 - y[1]*s0;
  o[1] = y[0]*s0 + y[1]*c0;
  o[2] = y[2]*c1 - y[3]*s1;
  o[3] = y[2]*s1 + y[3]*c1;
  st4(tp, o);
}

// ---- MFMA GEMM, XOR-swizzled LDS, ping-pong double-buffer (stage tile t+1 via
// global_load_lds while computing tile t; single barrier per K-tile whose
// implicit pre-barrier vmcnt(0) drains the prefetch). EPI: 0=plain bf16 C,
// 1=silu-pair -> g[.][2816], 2=residual -> d_out (reads x2, gate).
template<int TM, int EPI>
__global__ __launch_bounds__(256) void k_gemm_mfma(const u16* A, int lda, const u16* BT, int ldb,
                                                   u16* C, int N, int K,
                                                   const float* x2, const float* mg,
                                                   void* outp, const u16* fcp){
  __shared__ __align__(16) u16 As[2][TM*64];
  __shared__ __align__(16) u16 Bs[2][128*64];
  int tid = threadIdx.x, lane = tid&63, w = tid>>6;
  int col = lane&15, quad = lane>>4;
  int row0 = blockIdx.y*TM, col0 = blockIdx.x*128;
  const u16* Ab = A  + (size_t)row0*lda;
  const u16* Bb = BT + (size_t)col0*ldb;
  constexpr int MI = TM/32;
  int wm = (w>>1)*(TM/2);
  int wn = (w&1)*64;
  f32x4 acc[MI][4];
  #pragma unroll
  for(int i=0;i<MI;i++)
    #pragma unroll
    for(int j=0;j<4;j++) acc[i][j] = (f32x4){0.f,0.f,0.f,0.f};

  const int T = K/64;
  // prologue: tile 0 -> buf 0
  {
    #pragma unroll
    for(int i=0;i<TM/32;i++){
      int c = i*256 + w*64 + lane;
      int r = c>>3, s = c&7, gs = s ^ (r&7);
      gl2lds16(Ab + (size_t)r*lda + gs*8, &As[0][0] + (size_t)c*8);
    }
    #pragma unroll
    for(int i=0;i<4;i++){
      int c = i*256 + w*64 + lane;
      int r = c>>3, s = c&7, gs = s ^ (r&7);
      gl2lds16(Bb + (size_t)r*ldb + gs*8, &Bs[0][0] + (size_t)c*8);
    }
  }
  __syncthreads();

  for(int t=0;t<T;t++){
    // prefetch tile t+1 into the other buffer (overlaps with compute below)
    if(t+1 < T){
      int k0 = (t+1)*64, b = (t+1)&1;
      #pragma unroll
      for(int i=0;i<TM/32;i++){
        int c = i*256 + w*64 + lane;
        int r = c>>3, s = c&7, gs = s ^ (r&7);
        gl2lds16(Ab + (size_t)r*lda + k0 + gs*8, &As[b][0] + (size_t)c*8);
      }
      #pragma unroll
      for(int i=0;i<4;i++){
        int c = i*256 + w*64 + lane;
        int r = c>>3, s = c&7, gs = s ^ (r&7);
        gl2lds16(Bb + (size_t)r*ldb + k0 + gs*8, &Bs[b][0] + (size_t)c*8);
      }
    }
    const u16* Ac = &As[t&1][0];
    const u16* Bc = &Bs[t&1][0];
    #pragma unroll
    for(int ks=0;ks<64;ks+=32){
      short8 af[MI], bfr[4];
      #pragma unroll
      for(int mi=0;mi<MI;mi++){
        int r = wm+mi*16+col;
        int sch = ((ks>>3) + quad) ^ (col&7);
        af[mi] = *reinterpret_cast<const short8*>(&Ac[r*64 + sch*8]);
      }
      #pragma unroll
      for(int ni=0;ni<4;ni++){
        int r = wn+ni*16+col;
        int sch = ((ks>>3) + quad) ^ (col&7);
        bfr[ni] = *reinterpret_cast<const short8*>(&Bc[r*64 + sch*8]);
      }
      #pragma unroll
      for(int mi=0;mi<MI;mi++)
        #pragma unroll
        for(int ni=0;ni<4;ni++)
          acc[mi][ni] = __builtin_amdgcn_mfma_f32_16x16x32_bf16(af[mi], bfr[ni], acc[mi][ni], 0,0,0);
    }
    // implicit s_waitcnt vmcnt(0) lgkmcnt(0) before s_barrier drains the
    // prefetch (which had the whole compute phase to land) and fences reads.
    __syncthreads();
  }
  if constexpr(EPI==0){
    #pragma unroll
    for(int mi=0;mi<MI;mi++)
      #pragma unroll
      for(int r=0;r<4;r++){
        size_t rowoff = (size_t)(row0+wm+mi*16+quad*4+r)*N + col0 + wn;
        #pragma unroll
        for(int ni=0;ni<4;ni++)
          C[rowoff + ni*16 + col] = f2bfr(acc[mi][ni][r]);
      }
  } else if constexpr(EPI==1){
    // acc[mi][0..1] = h1 cols, acc[mi][2..3] = matching h3 cols
    int cb = blockIdx.x*64 + (wn?32:0) + col;
    #pragma unroll
    for(int mi=0;mi<MI;mi++)
      #pragma unroll
      for(int r=0;r<4;r++){
        int row = row0+wm+mi*16+quad*4+r;
        u16* gp = C + (size_t)row*HID_ + cb;
        #pragma unroll
        for(int ni=0;ni<2;ni++){
          float a = acc[mi][ni][r], cc = acc[mi][ni+2][r];
          float sv = a * __builtin_amdgcn_rcpf(1.f + __builtin_amdgcn_exp2f(-1.4426950f*a));
          gp[ni*16] = f2bfr(sv*cc);
        }
      }
  } else {
    bool f32o = is_f32(fcp);
    #pragma unroll
    for(int mi=0;mi<MI;mi++)
      #pragma unroll
      for(int r=0;r<4;r++){
        int row = row0+wm+mi*16+quad*4+r;
        int b = row >> 11;
        #pragma unroll
        for(int ni=0;ni<4;ni++){
          int cc = col0 + wn + ni*16 + col;
          float v = x2[(size_t)row*D_ + cc] + mg[b*6144 + 5120 + cc]*acc[mi][ni][r];
          if(f32o) ((float*)outp)[(size_t)row*D_ + cc] = v;
          else     ((u16*)outp)[(size_t)row*D_ + cc]   = f2bfr(v);
        }
      }
  }
}

// ---- V transpose: vt[(b*H+h)][hd][key] <- v[(b*S+key)*vstr + h*64+hd]
__global__ __launch_bounds__(256) void k_vt(const u16* v, int vstr, u16* vt){
  __shared__ u16 L[64][72];
  int tid = threadIdx.x;
  int wg = blockIdx.x;
  int kblk = wg & 31; int bh = wg >> 5; int h = bh & 15, b = bh >> 4;
  int row = tid>>2, c0 = (tid&3)*16;
  const u16* src = v + (size_t)(b*S_ + kblk*64 + row)*vstr + h*HD_ + c0;
  *reinterpret_cast<short8*>(&L[row][c0])   = *reinterpret_cast<const short8*>(src);
  *reinterpret_cast<short8*>(&L[row][c0+8]) = *reinterpret_cast<const short8*>(src+8);
  __syncthreads();
  int hd = tid>>2, k0 = (tid&3)*16;
  u16 tmp[16];
  #pragma unroll
  for(int j=0;j<16;j++) tmp[j] = L[k0+j][hd];
  u16* dst = vt + ((size_t)bh*HD_ + hd)*S_ + kblk*64 + k0;
  *reinterpret_cast<short8*>(dst)   = *reinterpret_cast<const short8*>(tmp);
  *reinterpret_cast<short8*>(dst+8) = *reinterpret_cast<const short8*>(tmp+8);
}

// ---- MFMA flash attention v7: 2 q-groups per wave (32 q-rows/wave): each ka/vf
// LDS read feeds 2 MFMAs, 2 independent softmax chains give in-wave ILP.
// s_setprio(1) around MFMA clusters (T5); XCD swizzle; ones-row l-sum; defer-max.
__global__ __launch_bounds__(256, 2) void k_attn_mfma(const u16* q, const u16* k, const u16* vt,
                                                      u16* o, int qks){
  __shared__ __align__(16) u16 Ks[2][64*64];
  __shared__ __align__(16) u16 Vs[2][64*64];
  int tid = threadIdx.x, lane = tid & 63, wid = tid >> 6;
  int col = lane & 15, quad = lane >> 4;
  int c7 = col & 7;
  // bijective XCD swizzle: 512 blocks = 8 XCDs x 64; same-(b,h) q-blocks stay on
  // one XCD so its K/V panel stays in that XCD's L2 (4 panels x 512KB < 4MB).
  int wg = ((blockIdx.x & 7) << 6) + (blockIdx.x >> 3);
  int qb = wg & 15; int bh = wg >> 4; int h = bh & 15, b = bh >> 4;

  const u16* kb  = k  + (size_t)b*S_*qks + h*HD_;
  const u16* vtb = vt + (size_t)bh*HD_*S_;

  short8 qa[2][2];   // [group][khalf]; Q pre-scaled by 0.125*log2(e)
  {
    const float qscale = 0.18033688f;
    const u16* qp = q + (size_t)(b*S_ + qb*128 + wid*16 + col)*qks + h*HD_ + quad*8;
    #pragma unroll
    for(int g=0;g<2;g++){
      short8 t0 = *reinterpret_cast<const short8*>(qp + (size_t)g*64*qks);
      short8 t1 = *reinterpret_cast<const short8*>(qp + (size_t)g*64*qks + 32);
      #pragma unroll
      for(int j=0;j<8;j++){
        qa[g][0][j] = (short)f2bf(bf2f((u16)t0[j])*qscale);
        qa[g][1][j] = (short)f2bf(bf2f((u16)t1[j])*qscale);
      }
    }
  }
  short8 vone;      // bf16 1.0 splat: A-operand of ones for the l-sum MFMA
  #pragma unroll
  for(int j=0;j<8;j++) vone[j] = (short)0x3F80;

  float m_i[2] = {-1e30f, -1e30f};
  f32x2 nm[2]; nm[0] = (f32x2){1e30f,1e30f}; nm[1] = (f32x2){1e30f,1e30f};
  f32x4 accl[2];
  accl[0] = (f32x4){0.f,0.f,0.f,0.f}; accl[1] = (f32x4){0.f,0.f,0.f,0.f};
  f32x4 acc[2][4];
  #pragma unroll
  for(int g=0;g<2;g++)
    #pragma unroll
    for(int t=0;t<4;t++) acc[g][t] = (f32x4){0.f,0.f,0.f,0.f};

  // staging: lds row l holds K global row kl(l) (MFMA permutation), with 16B
  // slot s of the row stored swizzled: LDS(l, s) = src(l)[s ^ (l&7)].
  int l0 = tid>>3;        // lds row, chunk half 0
  int l1 = 32 + l0;       // chunk half 1 (l1&7 == l0&7)
  int gs = ((tid&7) ^ (l0&7))*8;   // swizzled source slot offset (u16)
  int kl0 = 32*(l0>>5) + 8*((l0>>2)&3) + 4*((l0>>4)&1) + (l0&3);
  int kl1 = 32*(l1>>5) + 8*((l1>>2)&3) + 4*((l1>>4)&1) + (l1&3);
  const u16* kp0 = kb + (size_t)kl0*qks + gs;
  const u16* kp1 = kb + (size_t)kl1*qks + gs;
  const u16* vp0 = vtb + (size_t)l0*S_ + gs;
  const u16* vp1 = vtb + (size_t)l1*S_ + gs;

  // prologue: stage chunk 0 into buf 0
  gl2lds16(kp0, &Ks[0][tid*8]);
  gl2lds16(kp1, &Ks[0][2048 + tid*8]);
  gl2lds16(vp0, &Vs[0][tid*8]);
  gl2lds16(vp1, &Vs[0][2048 + tid*8]);

  for(int i=0;i<32;i++){
    __syncthreads();
    const u16* Kc = Ks[i&1];
    const u16* Vc = Vs[i&1];
    if(i < 31){
      size_t off = (size_t)(i+1)*64;
      u16* Kn = (u16*)Ks[(i+1)&1];
      u16* Vn = (u16*)Vs[(i+1)&1];
      gl2lds16(kp0 + off*qks, &Kn[tid*8]);
      gl2lds16(kp1 + off*qks, &Kn[2048 + tid*8]);
      gl2lds16(vp0 + off,     &Vn[tid*8]);
      gl2lds16(vp1 + off,     &Vn[2048 + tid*8]);
    }

    f32x4 st[2][4];
    __builtin_amdgcn_s_setprio(1);
    #pragma unroll
    for(int mt=0;mt<4;mt++){
      short8 ka0 = *reinterpret_cast<const short8*>(&Kc[(mt*16+col)*64 + ((quad  ) ^ c7)*8]);
      short8 ka1 = *reinterpret_cast<const short8*>(&Kc[(mt*16+col)*64 + ((quad+4) ^ c7)*8]);
      f32x4 z = (f32x4){0.f,0.f,0.f,0.f};
      st[0][mt] = __builtin_amdgcn_mfma_f32_16x16x32_bf16(ka0, qa[0][0], z, 0,0,0);
      st[1][mt] = __builtin_amdgcn_mfma_f32_16x16x32_bf16(ka0, qa[1][0], z, 0,0,0);
      st[0][mt] = __builtin_amdgcn_mfma_f32_16x16x32_bf16(ka1, qa[0][1], st[0][mt], 0,0,0);
      st[1][mt] = __builtin_amdgcn_mfma_f32_16x16x32_bf16(ka1, qa[1][1], st[1][mt], 0,0,0);
    }
    __builtin_amdgcn_s_setprio(0);

    u32x4 pws[2][2];
    #pragma unroll
    for(int g=0;g<2;g++){
      // row max: v_max3 tree + permlane cross-quad combine (VALU only)
      float t0 = vmax3(st[g][0][0], st[g][0][1], st[g][0][2]);
      float t1 = vmax3(st[g][0][3], st[g][1][0], st[g][1][1]);
      float t2 = vmax3(st[g][1][2], st[g][1][3], st[g][2][0]);
      float t3 = vmax3(st[g][2][1], st[g][2][2], st[g][2][3]);
      float t4 = vmax3(st[g][3][0], st[g][3][1], st[g][3][2]);
      float cm = fmaxf(vmax3(t0, t1, t2), vmax3(t3, t4, st[g][3][3]));
      { float a, bb2; plswap16(cm, a, bb2); cm = fmaxf(a, bb2);
        plswap32(cm, a, bb2); cm = fmaxf(a, bb2); }
      // defer-max: rescale only when the max grew by >8 (P bounded by 2^8)
      if(__any(cm - m_i[g] > 8.f)){
        float mn = fmaxf(m_i[g], cm);
        float al = __builtin_amdgcn_exp2f(m_i[g] - mn);
        m_i[g] = mn;
        nm[g] = (f32x2){-mn, -mn};
        accl[g][0] *= al;
        #pragma unroll
        for(int t=0;t<4;t++) acc[g][t] *= al;
      }
      float pe[4][4];
      #pragma unroll
      for(int mt=0;mt<4;mt++){
        f32x2 lo = pkadd(st[g][mt].xy, nm[g]);
        f32x2 hi = pkadd(st[g][mt].zw, nm[g]);
        pe[mt][0] = __builtin_amdgcn_exp2f(lo.x);
        pe[mt][1] = __builtin_amdgcn_exp2f(lo.y);
        pe[mt][2] = __builtin_amdgcn_exp2f(hi.x);
        pe[mt][3] = __builtin_amdgcn_exp2f(hi.y);
      }
      #pragma unroll
      for(int w=0;w<2;w++){
        pws[g][w][0] = cvtpk(pe[2*w][0],   pe[2*w][1]);
        pws[g][w][1] = cvtpk(pe[2*w][2],   pe[2*w][3]);
        pws[g][w][2] = cvtpk(pe[2*w+1][0], pe[2*w+1][1]);
        pws[g][w][3] = cvtpk(pe[2*w+1][2], pe[2*w+1][3]);
      }
    }

    // PV + l-sum on the matrix pipe; each vf read feeds both q-groups
    __builtin_amdgcn_s_setprio(1);
    #pragma unroll
    for(int w=0;w<2;w++){
      short8 pb0 = *reinterpret_cast<short8*>(&pws[0][w]);
      short8 pb1 = *reinterpret_cast<short8*>(&pws[1][w]);
      #pragma unroll
      for(int ht=0;ht<4;ht++){
        short8 vf = *reinterpret_cast<const short8*>(&Vc[(ht*16+col)*64 + ((w*4+quad) ^ c7)*8]);
        acc[0][ht] = __builtin_amdgcn_mfma_f32_16x16x32_bf16(vf, pb0, acc[0][ht], 0,0,0);
        acc[1][ht] = __builtin_amdgcn_mfma_f32_16x16x32_bf16(vf, pb1, acc[1][ht], 0,0,0);
      }
      accl[0] = __builtin_amdgcn_mfma_f32_16x16x32_bf16(vone, pb0, accl[0], 0,0,0);
      accl[1] = __builtin_amdgcn_mfma_f32_16x16x32_bf16(vone, pb1, accl[1], 0,0,0);
    }
    __builtin_amdgcn_s_setprio(0);
  }
  // accl[g][0] is the lane's full denominator (D rows all equal sum_k P[k][col])
  #pragma unroll
  for(int g=0;g<2;g++){
    float inv = __builtin_amdgcn_rcpf(accl[g][0]);
    u16* ob = o + (size_t)(b*S_ + qb*128 + g*64 + wid*16 + col)*D_ + h*HD_;
    #pragma unroll
    for(int ht=0;ht<4;ht++){
      uint2 t;
      t.x = cvtpk(acc[g][ht][0]*inv, acc[g][ht][1]*inv);
      t.y = cvtpk(acc[g][ht][2]*inv, acc[g][ht][3]*inv);
      *reinterpret_cast<uint2*>(ob + ht*16 + quad*4) = t;
    }
  }
}

extern "C" void kernel_launch(void* const* d_in, const int* in_sizes, int n_in,
                              void* d_out, int out_size, void* d_ws, size_t ws_size,
                              hipStream_t stream){
  const void* x   = d_in[0];
  const void* ada = d_in[1];
  const void* fc  = d_in[2];
  const void* fs  = d_in[3];
  const void* wq  = d_in[4];
  const void* wk  = d_in[5];
  const void* wv  = d_in[6];
  const void* wo  = d_in[7];
  const void* qnw = d_in[8];
  const void* qnb = d_in[9];
  const void* knw = d_in[10];
  const void* knb = d_in[11];
  const void* anw = d_in[12];
  const void* fnw = d_in[13];
  const void* aw  = d_in[14];
  const void* ab  = d_in[15];
  const void* w1  = d_in[16];
  const void* w2  = d_in[17];
  const void* w3  = d_in[18];
  char* ws = (char*)d_ws;
  const size_t MB = 1u<<20;
  const u16* fcp = (const u16*)fc;

  // Workspace (74MB), lifetime-checked:
  //  m     4KB..52KB
  //  hbuf  1..9MB    h (d3) -> attn-out (d7) -> h2 (d9)
  //  xqkv  9..33MB   [4096][3072] bf16, written d4, dead after d7 (attn).
  //                  x2 fp32 aliases 9..25 (written d9); proj aliases 25..33
  //                  (written d8, AFTER xqkv is dead).
  //  woT   33..35MB  written d1, read d8
  //  w13T  35..46MB  written d1, read d10
  //  w2T   46..52MB  written d1, read d11
  //  g     52..74MB  written d10, read d11.
  //                  qkvT aliases g+0 (52..58; written d1, dead after d4).
  //                  vt   aliases g+6MB (58..66; written d6, dead after d7).
  //                  Both dead before g is written at d10. vt does NOT overlap
  //                  live xqkv (the r6 bug).
  float* m    = (float*)(ws + 4096);
  u16*  hbuf  = (u16*)(ws + 1*MB);
  u16*  xqkv  = (u16*)(ws + 9*MB);
  float* x2   = (float*)(ws + 9*MB);
  u16*  proj  = (u16*)(ws + 25*MB);
  u16*  woT   = (u16*)(ws + 33*MB);
  u16*  w13T  = (u16*)(ws + 35*MB);
  u16*  w2T   = (u16*)(ws + 46*MB);
  u16*  g     = (u16*)(ws + 52*MB);
  u16*  qkvT  = (u16*)(ws + 52*MB);   // aliases g head; dead before g written
  u16*  vt    = (u16*)(ws + 58*MB);   // aliases g+6MB; dead before g written

  dim3 blk(256);

  // d1: one launch: all weight transposes + zero m
  k_wtall<<<dim3(3184), blk, 0, stream>>>(wq, wk, wv, wo, w1, w3, w2,
                                          qkvT, woT, w13T, w2T, fcp, m);
  // d2, d3
  k_adaln<<<dim3(24,8), blk, 0, stream>>>(ada, aw, ab, m, fcp);
  k_rms_mod<<<dim3(B_*S_), blk, 0, stream>>>(x, anw, m, hbuf, 0, 1024, fcp);

  // d4: fused QKV
  k_gemm_mfma<128,0><<<dim3(24,32), blk, 0, stream>>>(hbuf, 1024, qkvT, 1024, xqkv,
                                                      3072, 1024, nullptr, nullptr, nullptr, fcp);
  // d5, d6, d7
  k_ln_rope2<<<dim3(B_*S_,2), blk, 0, stream>>>(xqkv, qnw, qnb, knw, knb, fc, fs);
  k_vt<<<dim3(B_*H_*S_/64), blk, 0, stream>>>(xqkv + 2048, 3072, vt);
  k_attn_mfma<<<dim3(B_*H_*S_/128), blk, 0, stream>>>(xqkv, xqkv + 1024, vt, hbuf, 3072);

  // d8, d9
  k_gemm_mfma<64,0><<<dim3(8,64), blk, 0, stream>>>(hbuf, 1024, woT, 1024, proj,
                                                    1024, 1024, nullptr, nullptr, nullptr, fcp);
  k_resid_rms<<<dim3(B_*S_), blk, 0, stream>>>(x, proj, m, fnw, x2, hbuf, fcp);

  // d10: fused w1|w3 with silu epilogue -> g
  k_gemm_mfma<128,1><<<dim3(44,32), blk, 0, stream>>>(hbuf, 1024, w13T, 1024, g,
                                                      5632, 1024, nullptr, nullptr, nullptr, fcp);
  // d11: w2 with fused residual epilogue -> d_out
  k_gemm_mfma<64,2><<<dim3(8,64), blk, 0, stream>>>(g, 2816, w2T, 2816, nullptr,
                                                    1024, 2816, x2, m, d_out, fcp);
}